// Round 14
// baseline (145.254 us; speedup 1.0000x reference)
//
#include <hip/hip_runtime.h>
#include <hip/hip_bf16.h>

// CIN (xDeepFM) fused 3-layer kernel for MI355X — R14: R13 K-split waves with
// the exchange-index bug fixed.
// R13 post-mortem: K-partial LDS exchange indexed by (reg, l31) WITHOUT half
// — but C/D row = (reg&3)+8*(reg>>2)+4*half, so the two half-waves collided
// on the same PS slot -> absmax 77. Fix: index includes half; exchange runs
// in two rounds (nt=0, barrier, nt=1) so PS stays 32KB (LDS total 80KB,
// same as R13 which launched fine).
// Design (R13): 4 waves/SIMD at R9's unchanged W traffic.
//   WG 1024 thr, 16 waves = (mrow 4) x (kh 2: K-half of each field) x
//   (npair 2), nt=2 batches/wave; each wave loads only its kq-half of W.
//   K-partials combined via LDS (kh1 writes, kh0 adds + epilogue).
// L2 = 16-wave U-trick (validated R10): out2[b,h] = (x0_b.S2_b^T) @ W2.
// Canary: WRITE_SIZE ~1.5MB / VGPR <= ~100. Spill is fatal here -> revert.

typedef __attribute__((ext_vector_type(8))) short short8;
typedef __attribute__((ext_vector_type(8))) __bf16 bf16x8;
typedef __attribute__((ext_vector_type(16))) float f32x16;
typedef __attribute__((ext_vector_type(4))) unsigned short u16x4;

#define DEVINL static __device__ __forceinline__

DEVINL unsigned short f2bf_rne(float f) {
  unsigned int u = __builtin_bit_cast(unsigned int, f);
  unsigned int r = u + 0x7fffu + ((u >> 16) & 1u);
  return (unsigned short)(r >> 16);
}

// async global->LDS, 16B per lane; LDS dest = wave-uniform base + lane*16
DEVINL void gload_lds16(const void* g, void* l) {
  __builtin_amdgcn_global_load_lds(
      (const __attribute__((address_space(1))) unsigned int*)g,
      (__attribute__((address_space(3))) unsigned int*)l, 16, 0, 0);
}

// MFMA adapter: builtin may want v8i16 or v8bf16. SFINAE both.
template <typename V>
DEVINL auto mfma_32x32x16_bf16(V a, V b, f32x16 c, int)
    -> decltype(__builtin_amdgcn_mfma_f32_32x32x16_bf16(a, b, c, 0, 0, 0)) {
  return __builtin_amdgcn_mfma_f32_32x32x16_bf16(a, b, c, 0, 0, 0);
}
template <typename V>
DEVINL f32x16 mfma_32x32x16_bf16(V a, V b, f32x16 c, long) {
  return __builtin_amdgcn_mfma_f32_32x32x16_bf16(
      __builtin_bit_cast(bf16x8, a), __builtin_bit_cast(bf16x8, b), c, 0, 0, 0);
}
DEVINL f32x16 mfma_bf16(short8 a, short8 b, f32x16 c) {
  return mfma_32x32x16_bf16(a, b, c, 0);
}

// ---------------- W pack kernel (unchanged, verified R2-R12) ----------------
// Packed layout per layer: [f][kb=k>>3][h][j=k&7] bf16 (granule = 1024 u16).
__global__ void pack_w_kernel(const float* __restrict__ W0,
                              const float* __restrict__ W1,
                              const float* __restrict__ W2,
                              unsigned short* __restrict__ Wt) {
  __shared__ float tile[8][132];
  const int u = blockIdx.x;
  const float* W; int FK, f, kb, base;
  if (u < 128)      { W = W0; FK = 32;  f = u >> 2;         kb = u & 3;          base = 0; }
  else if (u < 640) { W = W1; FK = 128; f = (u - 128) >> 4; kb = (u - 128) & 15; base = 131072; }
  else              { W = W2; FK = 128; f = (u - 640) >> 4; kb = (u - 640) & 15; base = 655360; }
  const int t = threadIdx.x;
#pragma unroll
  for (int i = 0; i < 4; ++i) {
    const int e = t + i * 256;  // 0..1023
    const int kk = e >> 7, h = e & 127;
    tile[kk][h] = W[(f * FK + kb * 8 + kk) * 128 + h];
  }
  __syncthreads();
  unsigned short* dst = Wt + base + f * (FK / 8) * 1024 + kb * 1024;
  const int h = t >> 1;
  const int j0 = (t & 1) * 4;
  u16x4 v;
  v.x = f2bf_rne(tile[j0 + 0][h]);
  v.y = f2bf_rne(tile[j0 + 1][h]);
  v.z = f2bf_rne(tile[j0 + 2][h]);
  v.w = f2bf_rne(tile[j0 + 3][h]);
  *(u16x4*)&dst[t * 4] = v;
}

// ---------------- layers 0/1: K-split waves ----------------
// KQH = kq's per wave (L0: 1, L1: 4). Wave owns kq = kh*KQH + i.
// W granule for (f, kq): kb = 2*kq + half; per-lane byte addr =
//   WtL + f*FSTRIDE + kh*KQH*4096 + i*4096 + half*2048 + (mrow*32+l31)*16.
template <int KQH, int LAYER>
DEVINL void run_layer(const unsigned short* __restrict__ WtL,
                      const float* __restrict__ bias,
                      const float* x0l,  // LDS x0 block [b][f][d]
                      float* __restrict__ outp, int outoff,
                      unsigned int* SB, float* PS,
                      int mrow, int npair, int kh, int l31, int half) {
  __syncthreads();  // state in SB + x0l ready

  // B-frags (S): sfr[nt][i] slot (half,j) = S[r][k = (kh*KQH+i)*16+half*8+j],
  // r = npair*64 + nt*32 + l31. SB row k2 packs (k even lo16, k odd hi16).
  int4 sfr[2][KQH];
  const int rb = npair * 64;
#pragma unroll
  for (int nt = 0; nt < 2; ++nt) {
    const int r = rb + nt * 32 + l31;
#pragma unroll
    for (int i = 0; i < KQH; ++i) {
      const int row0 = (kh * KQH + i) * 8 + half * 4;
      int4 v;
      v.x = (int)SB[(row0 + 0) * 128 + r];
      v.y = (int)SB[(row0 + 1) * 128 + r];
      v.z = (int)SB[(row0 + 2) * 128 + r];
      v.w = (int)SB[(row0 + 3) * 128 + r];
      sfr[nt][i] = v;
    }
  }

  f32x16 zv;
#pragma unroll
  for (int e = 0; e < 16; ++e) zv[e] = 0.f;
  f32x16 acc[2] = {zv, zv};

  constexpr int FSTRIDE = KQH * 8192;  // bytes per field in packed W
  const char* gp = (const char*)WtL +
                   (size_t)(kh * KQH * 4096 + half * 2048 +
                            (mrow * 32 + l31) * 16);
  const int xb0 = (npair * 2) * 1024 + l31;
  const int xb1 = xb0 + 1024;

  short8 qa[KQH];
#pragma unroll
  for (int i = 0; i < KQH; ++i)
    qa[i] = *(const short8*)(gp + i * 4096);
  float xs0 = x0l[xb0], xs1 = x0l[xb1];
  __syncthreads();  // all waves hold sfr; SB free for this layer's epilogue

#pragma unroll 1
  for (int f = 0; f < 32; ++f) {
    f32x16 Y;
#pragma unroll
    for (int i = 0; i < KQH; ++i) {  // batch 0 chain
      const short8 s = __builtin_bit_cast(short8, sfr[0][i]);
      Y = mfma_bf16(qa[i], s, i == 0 ? zv : Y);
    }
#pragma unroll
    for (int e = 0; e < 16; ++e) acc[0][e] += xs0 * Y[e];
#pragma unroll
    for (int i = 0; i < KQH; ++i) {  // batch 1 chain (qa reads done after)
      const short8 s = __builtin_bit_cast(short8, sfr[1][i]);
      Y = mfma_bf16(qa[i], s, i == 0 ? zv : Y);
    }
    if (f < 31) {  // reissue same regs: all qa reads have issued (WAR-safe)
      gp += FSTRIDE;
#pragma unroll
      for (int i = 0; i < KQH; ++i)
        qa[i] = *(const short8*)(gp + i * 4096);
    }
#pragma unroll
    for (int e = 0; e < 16; ++e) acc[1][e] += xs1 * Y[e];
    if (f < 31) {  // next field's xs (LDS; 1-field distance)
      xs0 = x0l[xb0 + (f + 1) * 32];
      xs1 = x0l[xb1 + (f + 1) * 32];
    }
  }

  // --- K-partial exchange, two rounds (32KB PS), HALF IN THE INDEX ---
  // slot = (mrow*2+npair)*1024 + (half*16+reg)*32 + l31  (8192 floats max)
  const int psb = (mrow * 2 + npair) * 1024 + half * 512 + l31;
#pragma unroll 1
  for (int nt = 0; nt < 2; ++nt) {
    if (kh == 1) {
#pragma unroll
      for (int reg = 0; reg < 16; ++reg)
        PS[psb + reg * 32] = acc[nt][reg];
    }
    __syncthreads();
    if (kh == 0) {
#pragma unroll
      for (int reg = 0; reg < 16; ++reg)
        acc[nt][reg] += PS[psb + reg * 32];
    }
    __syncthreads();
  }

  if (kh == 0) {
    // --- epilogue (kh0 only) ---
    // C/D: col = lane&31 = n; row = (reg&3)+8*(reg>>2)+4*half = h-in-tile.
    float bv[16];
#pragma unroll
    for (int e = 0; e < 16; ++e)
      bv[e] = bias[mrow * 32 + (e & 3) + 8 * (e >> 2) + 4 * half];

    if constexpr (LAYER < 2) {
      // next state S'[r][h] = bf16(acc+bias), packed [h/2][r] u32 into SB
#pragma unroll
      for (int nt = 0; nt < 2; ++nt) {
        const int r = rb + nt * 32 + l31;
#pragma unroll
        for (int g = 0; g < 4; ++g) {
          const int h2 = mrow * 16 + 4 * g + 2 * half;
          const float v0 = acc[nt][4 * g + 0] + bv[4 * g + 0];
          const float v1 = acc[nt][4 * g + 1] + bv[4 * g + 1];
          const float v2 = acc[nt][4 * g + 2] + bv[4 * g + 2];
          const float v3 = acc[nt][4 * g + 3] + bv[4 * g + 3];
          SB[h2 * 128 + r] =
              (unsigned)f2bf_rne(v0) | ((unsigned)f2bf_rne(v1) << 16);
          SB[(h2 + 1) * 128 + r] =
              (unsigned)f2bf_rne(v2) | ((unsigned)f2bf_rne(v3) << 16);
        }
      }
    }

    // final output: out[b, outoff+h] = sum_d acc + 32*bias (d = l31 lanes)
#pragma unroll
    for (int nt = 0; nt < 2; ++nt) {
      float sv[16];
#pragma unroll
      for (int e = 0; e < 16; ++e) {
        float v = acc[nt][e];
        v += __shfl_xor(v, 1);
        v += __shfl_xor(v, 2);
        v += __shfl_xor(v, 4);
        v += __shfl_xor(v, 8);
        v += __shfl_xor(v, 16);
        sv[e] = v + 32.0f * bv[e];
      }
      if (l31 == 0) {
        const int b = npair * 2 + nt;
#pragma unroll
        for (int g = 0; g < 4; ++g) {
          const int h = mrow * 32 + 8 * g + 4 * half;
          float4 o = {sv[4 * g + 0], sv[4 * g + 1], sv[4 * g + 2],
                      sv[4 * g + 3]};
          *(float4*)&outp[b * 384 + outoff + h] = o;
        }
      }
    }
  }
}

// ---------------- layer 2, U-trick (R10's validated 16-wave version) -------
// out2[b,h] = sum_k U[b,k]*W2[k,h] + 32*b2[h];  U[b,f*128+g] = x0_b . S2_b^T.
DEVINL void run_layer2_fast(const unsigned short* __restrict__ WtL,
                            const float* __restrict__ bias,
                            const float* x0l,
                            float* __restrict__ outp,
                            unsigned int* SB, float* PS,
                            int w, int l31, int half, int tid) {
  __syncthreads();  // S2 in SB ready ([h/2][r=b*32+d] u32 bf16-pairs)

  f32x16 zv;
#pragma unroll
  for (int e = 0; e < 16; ++e) zv[e] = 0.f;

  // ---- step 1: U_b = x0_b (32f x 32d) . S2_b^T (32d x 128g) ----
  // wave w: batch bw = w>>2, g-tile gt = w&3.
  const int bw = w >> 2, gt = w & 3;
  short8 a1[2];
  {
    const float* xr = &x0l[bw * 1024 + l31 * 32];
#pragma unroll
    for (int kq = 0; kq < 2; ++kq) {
      const int d0 = kq * 16 + half * 8;
      union { short8 v; unsigned short u[8]; } t;
#pragma unroll
      for (int j = 0; j < 8; ++j) t.u[j] = f2bf_rne(xr[d0 + j]);
      a1[kq] = t.v;
    }
  }
  short8 bfr[2];  // B[k=d][n=g]: S2[b, g=gt*32+l31, d]
  {
    const int g = gt * 32 + l31;
    const unsigned int* row = &SB[(g >> 1) * 128 + bw * 32];
    const int sh = (g & 1) * 16;
#pragma unroll
    for (int kq = 0; kq < 2; ++kq) {
      const int d0 = kq * 16 + half * 8;
      union { short8 v; unsigned short u[8]; } t;
#pragma unroll
      for (int j = 0; j < 8; ++j)
        t.u[j] = (unsigned short)(row[d0 + j] >> sh);
      bfr[kq] = t.v;
    }
  }
  f32x16 ua = mfma_bf16(a1[0], bfr[0], zv);
  ua = mfma_bf16(a1[1], bfr[1], ua);
  __syncthreads();  // all waves done reading S2 from SB

  // ---- write U into SB as U32[k2 = k/2][b] (u16 writes; k = f*128+g) ----
  unsigned short* U16 = (unsigned short*)SB;
  {
    const int g = gt * 32 + l31;
#pragma unroll
    for (int reg = 0; reg < 16; ++reg) {
      const int f = (reg & 3) + 8 * (reg >> 2) + 4 * half;
      const int k = f * 128 + g;
      U16[(k >> 1) * 8 + bw * 2 + (k & 1)] = f2bf_rne(ua[reg]);
    }
  }
  __syncthreads();  // U ready

  // ---- step 2: D[m=h][n=b] = sum_k W2[k,h]*U[b,k] ----
  // wave: mt = w&3 (h-tile), kh4 = w>>2 (k quarter: 16 quads = 64 kq).
  const int mt = w & 3, kh4 = w >> 2;
  const char* gb = (const char*)WtL +
                   (size_t)(half * 2048 + (mt * 32 + l31) * 16);
  const int bl = l31 & 3;  // lanes 4..31 duplicate b (cols unused)

  auto ldq2 = [&](short8* wv, int q) {  // quad q -> kq = 4q..4q+3
#pragma unroll
    for (int i = 0; i < 4; ++i)
      wv[i] = *(const short8*)(gb + (size_t)q * 16384 + i * 4096);
  };
  auto breadq = [&](short8* bv, int q) {
#pragma unroll
    for (int i = 0; i < 4; ++i) {
      const int row0 = (q * 4 + i) * 8 + half * 4;
      int4 v;
      v.x = (int)SB[(row0 + 0) * 4 + bl];
      v.y = (int)SB[(row0 + 1) * 4 + bl];
      v.z = (int)SB[(row0 + 2) * 4 + bl];
      v.w = (int)SB[(row0 + 3) * 4 + bl];
      bv[i] = __builtin_bit_cast(short8, v);
    }
  };

  f32x16 acc0 = zv, acc1 = zv;
  short8 qa[4], qb[4], Ba[4], Bb[4];
  const int q0 = kh4 * 16;  // 16 quads per wave
  ldq2(qa, q0);
  breadq(Ba, q0);
#pragma unroll 1
  for (int qq = 0; qq < 8; ++qq) {
    const int q = q0 + 2 * qq;
    ldq2(qb, q + 1);
    breadq(Bb, q + 1);
#pragma unroll
    for (int i = 0; i < 4; ++i) acc0 = mfma_bf16(qa[i], Ba[i], acc0);
    if (qq < 7) {
      ldq2(qa, q + 2);
      breadq(Ba, q + 2);
    }
#pragma unroll
    for (int i = 0; i < 4; ++i) acc1 = mfma_bf16(qb[i], Bb[i], acc1);
  }
#pragma unroll
  for (int e = 0; e < 16; ++e) acc0[e] += acc1[e];

  __syncthreads();  // all waves done reading U from SB

  // ---- partials P[(b*128+h)*4 + kh4] f32 into PS (8KB), then reduce ----
  float* P = PS;
  if (l31 < 4) {  // b = l31
#pragma unroll
    for (int reg = 0; reg < 16; ++reg) {
      const int h = mt * 32 + (reg & 3) + 8 * (reg >> 2) + 4 * half;
      P[(l31 * 128 + h) * 4 + kh4] = acc0[reg];
    }
  }
  __syncthreads();
  if (tid < 512) {
    const int b = tid >> 7, h = tid & 127;
    const float v = P[tid * 4] + P[tid * 4 + 1] + P[tid * 4 + 2] +
                    P[tid * 4 + 3] + 32.0f * bias[h];
    outp[b * 384 + 256 + h] = v;
  }
}

__global__ __launch_bounds__(1024, 1) void cin_kernel(
    const float* __restrict__ x0g, const unsigned short* __restrict__ Wt,
    const float* __restrict__ b0, const float* __restrict__ b1,
    const float* __restrict__ b2, float* __restrict__ out) {
  __shared__ unsigned int SB[64 * 128];        // 32KB state / U
  __shared__ __align__(16) float x0l[4096];    // 16KB x0 block [b][f][d]
  __shared__ float PS[8192];                   // 32KB K-partial exchange / P

  const int t = threadIdx.x;
  const int lane = t & 63;
  const int w = t >> 6;          // 0..15
  const int mrow = w & 3;        // h-tile of 32
  const int kh = (w >> 2) & 1;   // K-half (L0/L1)
  const int npair = w >> 3;      // batch pair
  const int l31 = lane & 31, half = lane >> 5;
  const int wgb0 = blockIdx.x * 4;  // 4 batches per WG

  // prologue A: stage x0 block -> LDS (16 chunks x 1KB)
  const float* xsrc = x0g + (size_t)wgb0 * 1024;
  gload_lds16(xsrc + w * 256 + lane * 4, x0l + w * 256);
  // prologue B: S1 = bf16(x0^T) -> SB ([g/2][r] u32, r = b_local*32+d)
#pragma unroll
  for (int s = 0; s < 2; ++s) {
    const int i = t + s * 1024;  // 0..2047
    const int r = i & 127, g2 = i >> 7;
    const float* p = &x0g[(wgb0 + (r >> 5)) * 1024 + (2 * g2) * 32 + (r & 31)];
    SB[g2 * 128 + r] =
        (unsigned)f2bf_rne(p[0]) | ((unsigned)f2bf_rne(p[32]) << 16);
  }
  // visibility handled by the entry barrier in run_layer (full drain)

  float* outp = out + (size_t)wgb0 * 384;
  run_layer<1, 0>(Wt, b0, x0l, outp, 0, SB, PS, mrow, npair, kh, l31, half);
  run_layer<4, 1>(Wt + 131072, b1, x0l, outp, 128, SB, PS,
                  mrow, npair, kh, l31, half);
  run_layer2_fast(Wt + 655360, b2, x0l, outp, SB, PS, w, l31, half, t);
}

extern "C" void kernel_launch(void* const* d_in, const int* in_sizes, int n_in,
                              void* d_out, int out_size, void* d_ws, size_t ws_size,
                              hipStream_t stream) {
  (void)in_sizes; (void)n_in; (void)out_size; (void)ws_size;
  const float* x0 = (const float*)d_in[0];
  const float* W0 = (const float*)d_in[1];
  const float* W1 = (const float*)d_in[2];
  const float* W2 = (const float*)d_in[3];
  const float* b0 = (const float*)d_in[4];
  const float* b1 = (const float*)d_in[5];
  const float* b2 = (const float*)d_in[6];
  unsigned short* Wt = (unsigned short*)d_ws;  // 2,359,296 B

  pack_w_kernel<<<1152, 256, 0, stream>>>(W0, W1, W2, Wt);
  // 256 WGs x 1024 thr = 1 WG/CU (16 waves, 4/SIMD), K-split waves
  cin_kernel<<<256, 1024, 0, stream>>>(x0, Wt, b0, b1, b2, (float*)d_out);
}